// Round 11
// baseline (477.642 us; speedup 1.0000x reference)
//
#include <hip/hip_runtime.h>
#include <math.h>

// ---------------------------------------------------------------------------
// 3-layer GCN, CSR-gather formulation.
// Round 11: CSR build de-latencified. fill[] pre-initialized to rp[] so the
// edge atomic returns the absolute slot (random rp load removed from the
// chain), and hist/build process 4 edges per thread (int4 loads, 4
// independent atomic chains in flight). k_build was 75us at 0.5% VALU --
// pure serial-chain latency.
// N=100000, E=1200000, F: 128 -> 64 -> 64 -> 40
// ---------------------------------------------------------------------------

static inline int cdiv(long a, int b) { return (int)((a + b - 1) / b); }

__global__ void k_zero_i32(int* __restrict__ p, int n) {
    int i = blockIdx.x * blockDim.x + threadIdx.x;
    if (i < n) p[i] = 0;
}

__global__ void k_hist4(const int* __restrict__ dst, int* __restrict__ cnt, int E) {
    int base = (blockIdx.x * blockDim.x + threadIdx.x) * 4;
    if (base >= E) return;
    if (base + 3 < E) {
        int4 d4 = *(const int4*)(dst + base);
        atomicAdd(&cnt[d4.x], 1);
        atomicAdd(&cnt[d4.y], 1);
        atomicAdd(&cnt[d4.z], 1);
        atomicAdd(&cnt[d4.w], 1);
    } else {
        for (int e = base; e < E; ++e) atomicAdd(&cnt[dst[e]], 1);
    }
}

__global__ void k_dis(const int* __restrict__ cnt, float* __restrict__ dis, int n) {
    int i = blockIdx.x * blockDim.x + threadIdx.x;
    if (i < n) dis[i] = rsqrtf(1.0f + (float)cnt[i]);  // +1 self-loop
}

// ---- 3-step exclusive scan of cnt[0..n) into rp[0..n], rp[n]=E ----
#define SCAN_B 1024
__global__ void k_scan1(const int* __restrict__ cnt, int* __restrict__ rp,
                        int* __restrict__ bsum, int n) {
    __shared__ int sm[SCAN_B];
    const int tid = threadIdx.x;
    const int gid = blockIdx.x * SCAN_B + tid;
    int v = (gid < n) ? cnt[gid] : 0;
    sm[tid] = v;
    __syncthreads();
    for (int off = 1; off < SCAN_B; off <<= 1) {
        int t = (tid >= off) ? sm[tid - off] : 0;
        __syncthreads();
        sm[tid] += t;
        __syncthreads();
    }
    if (gid < n) rp[gid] = sm[tid] - v;           // exclusive
    if (tid == SCAN_B - 1) bsum[blockIdx.x] = sm[tid];
}

__global__ void k_scan2(int* __restrict__ bsum, int nb) {
    __shared__ int sm[SCAN_B];
    const int tid = threadIdx.x;
    int v = (tid < nb) ? bsum[tid] : 0;
    sm[tid] = v;
    __syncthreads();
    for (int off = 1; off < SCAN_B; off <<= 1) {
        int t = (tid >= off) ? sm[tid - off] : 0;
        __syncthreads();
        sm[tid] += t;
        __syncthreads();
    }
    if (tid < nb) bsum[tid] = sm[tid] - v;        // exclusive
}

// rp finalize + fill init (fill[i] = rp[i] so build's atomic yields the slot)
__global__ void k_scan3(int* __restrict__ rp, const int* __restrict__ bsum,
                        int* __restrict__ fill, int n, int E) {
    const int gid = blockIdx.x * SCAN_B + threadIdx.x;
    if (gid < n) {
        int v = rp[gid] + bsum[gid / SCAN_B];
        rp[gid] = v;
        fill[gid] = v;
    }
    if (gid == n) rp[n] = E;
}

// scatter src index into CSR slots; 4 edges/thread, absolute-slot atomics
__global__ void k_build4(const int* __restrict__ src, const int* __restrict__ dst,
                         int* __restrict__ fill, int* __restrict__ esrc, int E) {
    int base = (blockIdx.x * blockDim.x + threadIdx.x) * 4;
    if (base >= E) return;
    if (base + 3 < E) {
        int4 d4 = *(const int4*)(dst + base);
        int4 s4 = *(const int4*)(src + base);
        int p0 = atomicAdd(&fill[d4.x], 1);
        int p1 = atomicAdd(&fill[d4.y], 1);
        int p2 = atomicAdd(&fill[d4.z], 1);
        int p3 = atomicAdd(&fill[d4.w], 1);
        esrc[p0] = s4.x;
        esrc[p1] = s4.y;
        esrc[p2] = s4.z;
        esrc[p3] = s4.w;
    } else {
        for (int e = base; e < E; ++e) {
            int p = atomicAdd(&fill[dst[e]], 1);
            esrc[p] = src[e];
        }
    }
}

__device__ __forceinline__ void fma4(float a, const float4& w, float4& acc) {
    acc.x = fmaf(a, w.x, acc.x);
    acc.y = fmaf(a, w.y, acc.y);
    acc.z = fmaf(a, w.z, acc.z);
    acc.w = fmaf(a, w.w, acc.w);
}

// LDS-tiled GEMM with fused dis-scale: Hs[N,64] = (X[N,K] @ W[K,64]) * dis[row].
template<int K>
__global__ __launch_bounds__(256, 2)
void k_gemm_lds(const float* __restrict__ X, const float* __restrict__ W,
                const float* __restrict__ dis, float* __restrict__ H, int N) {
    constexpr int KP = K + 4;                 // padded X row stride (floats)
    __shared__ float xs[64 * KP];
    __shared__ float wsh[K * 64];
    const int tid = threadIdx.x;
    const int tx = tid & 15;                  // col group (4 cols)
    const int ty = tid >> 4;                  // row group (4 rows)
    const int row0 = blockIdx.x * 64;

    // stage W: K*16 float4, fully coalesced
    {
        const float4* Wg = (const float4*)W;
        float4* Wl = (float4*)wsh;
#pragma unroll
        for (int i = 0; i < K * 16 / 256; ++i)
            Wl[i * 256 + tid] = Wg[i * 256 + tid];
    }
    // stage X tile: 64 rows x K floats (row-clamped), padded LDS rows
    {
        constexpr int F4 = K / 4;             // float4 per row
        for (int i = tid; i < 64 * F4; i += 256) {
            int r = i / F4, c = i - r * F4;
            int gr = min(row0 + r, N - 1);
            float4 v = *(const float4*)(X + (size_t)gr * K + c * 4);
            *(float4*)(xs + r * KP + c * 4) = v;
        }
    }
    __syncthreads();

    float4 acc0 = {0.f, 0.f, 0.f, 0.f};
    float4 acc1 = {0.f, 0.f, 0.f, 0.f};
    float4 acc2 = {0.f, 0.f, 0.f, 0.f};
    float4 acc3 = {0.f, 0.f, 0.f, 0.f};

    const float* xr0 = xs + (ty * 4 + 0) * KP;
    const float* xr1 = xs + (ty * 4 + 1) * KP;
    const float* xr2 = xs + (ty * 4 + 2) * KP;
    const float* xr3 = xs + (ty * 4 + 3) * KP;

#pragma unroll 2
    for (int k = 0; k < K; k += 4) {
        float4 w0 = *(const float4*)(wsh + (k + 0) * 64 + tx * 4);
        float4 w1 = *(const float4*)(wsh + (k + 1) * 64 + tx * 4);
        float4 w2 = *(const float4*)(wsh + (k + 2) * 64 + tx * 4);
        float4 w3 = *(const float4*)(wsh + (k + 3) * 64 + tx * 4);
        float4 xa = *(const float4*)(xr0 + k);
        float4 xb = *(const float4*)(xr1 + k);
        float4 xc = *(const float4*)(xr2 + k);
        float4 xd = *(const float4*)(xr3 + k);

        fma4(xa.x, w0, acc0); fma4(xa.y, w1, acc0); fma4(xa.z, w2, acc0); fma4(xa.w, w3, acc0);
        fma4(xb.x, w0, acc1); fma4(xb.y, w1, acc1); fma4(xb.z, w2, acc1); fma4(xb.w, w3, acc1);
        fma4(xc.x, w0, acc2); fma4(xc.y, w1, acc2); fma4(xc.z, w2, acc2); fma4(xc.w, w3, acc2);
        fma4(xd.x, w0, acc3); fma4(xd.y, w1, acc3); fma4(xd.z, w2, acc3); fma4(xd.w, w3, acc3);
    }

    const int r = row0 + ty * 4;
    float* hp = H + (size_t)r * 64 + tx * 4;
    if (r + 0 < N) { float d0 = dis[r + 0];
        acc0.x *= d0; acc0.y *= d0; acc0.z *= d0; acc0.w *= d0;
        *(float4*)(hp + 0 * 64) = acc0; }
    if (r + 1 < N) { float d1 = dis[r + 1];
        acc1.x *= d1; acc1.y *= d1; acc1.z *= d1; acc1.w *= d1;
        *(float4*)(hp + 1 * 64) = acc1; }
    if (r + 2 < N) { float d2 = dis[r + 2];
        acc2.x *= d2; acc2.y *= d2; acc2.z *= d2; acc2.w *= d2;
        *(float4*)(hp + 2 * 64) = acc2; }
    if (r + 3 < N) { float d3 = dis[r + 3];
        acc3.x *= d3; acc3.y *= d3; acc3.z *= d3; acc3.w *= d3;
        *(float4*)(hp + 3 * 64) = acc3; }
}

// Wave-per-node segmented row-sum, quad-per-edge.
// Input Hs = h*dis.  t = dis[d] * (Hs[d] + sum_{in-edges} Hs[s]).
// MODE 0: A = relu(t + bias)              (layer 1)
// MODE 1: A = relu(t + bias) * dis[d]     (layer 2 -> pre-scaled for layer-3 agg)
// MODE 2: A = t                           (layer 3 pre-GEMM aggregate)
template<int MODE>
__global__ __launch_bounds__(256, 8)
void k_agg(const float* __restrict__ Hs, const float* __restrict__ dis,
           const int* __restrict__ rp, const int* __restrict__ esrc,
           const float* __restrict__ bias, float* __restrict__ A, int N) {
    const int wave = threadIdx.x >> 6;
    const int lane = threadIdx.x & 63;
    const int node = blockIdx.x * (blockDim.x >> 6) + wave;
    if (node >= N) return;
    const int q  = lane >> 4;          // quad 0..3 -> interleaved edges
    const int f4 = lane & 15;          // float4 index within the 64-f row

    const int e0 = rp[node];
    const int e1 = rp[node + 1];
    float4 acc = {0.f, 0.f, 0.f, 0.f};
    int e = e0 + q;
    for (; e + 4 < e1; e += 8) {       // 2 edges per quad per round: 8 rows in flight
        int s0 = esrc[e];
        int s1 = esrc[e + 4];
        float4 h0 = *(const float4*)(Hs + (size_t)s0 * 64 + f4 * 4);
        float4 h1 = *(const float4*)(Hs + (size_t)s1 * 64 + f4 * 4);
        acc.x += h0.x + h1.x;
        acc.y += h0.y + h1.y;
        acc.z += h0.z + h1.z;
        acc.w += h0.w + h1.w;
    }
    for (; e < e1; e += 4) {
        int s = esrc[e];
        float4 h = *(const float4*)(Hs + (size_t)s * 64 + f4 * 4);
        acc.x += h.x; acc.y += h.y; acc.z += h.z; acc.w += h.w;
    }
    // cross-quad reduce (after: lanes 0..15 hold the full row sum)
    acc.x += __shfl_xor(acc.x, 16, 64);
    acc.y += __shfl_xor(acc.y, 16, 64);
    acc.z += __shfl_xor(acc.z, 16, 64);
    acc.w += __shfl_xor(acc.w, 16, 64);
    acc.x += __shfl_xor(acc.x, 32, 64);
    acc.y += __shfl_xor(acc.y, 32, 64);
    acc.z += __shfl_xor(acc.z, 32, 64);
    acc.w += __shfl_xor(acc.w, 32, 64);

    if (lane < 16) {
        const float dd = dis[node];
        float4 self = *(const float4*)(Hs + (size_t)node * 64 + lane * 4);
        float4 v;
        v.x = (acc.x + self.x) * dd;
        v.y = (acc.y + self.y) * dd;
        v.z = (acc.z + self.z) * dd;
        v.w = (acc.w + self.w) * dd;
        if (MODE == 0 || MODE == 1) {
            float4 bv = ((const float4*)bias)[lane];
            v.x = fmaxf(v.x + bv.x, 0.f);
            v.y = fmaxf(v.y + bv.y, 0.f);
            v.z = fmaxf(v.z + bv.z, 0.f);
            v.w = fmaxf(v.w + bv.w, 0.f);
        }
        if (MODE == 1) { v.x *= dd; v.y *= dd; v.z *= dd; v.w *= dd; }
        *(float4*)(A + (size_t)node * 64 + lane * 4) = v;
    }
}

// Final layer: out[n,:40] = log_softmax(X[n,:64] @ W3 + b3).
// Lane c holds W3[:,c] in 64 VGPRs; X row via wave-uniform loads.
__global__ __launch_bounds__(256, 4)
void k_w3lsm(const float* __restrict__ X, const float* __restrict__ W,
             const float* __restrict__ bias, float* __restrict__ out,
             int N, int npw) {
    const int wid  = blockIdx.x * (blockDim.x >> 6) + (threadIdx.x >> 6);
    const int lane = threadIdx.x & 63;
    const int cl   = (lane < 40) ? lane : 0;

    float w[64];
#pragma unroll
    for (int k = 0; k < 64; ++k) w[k] = W[k * 40 + cl];
    const float bv = bias[cl];

    const int n0 = wid * npw;
    const int n1 = min(n0 + npw, N);
    for (int node = n0; node < n1; ++node) {
        const int un = __builtin_amdgcn_readfirstlane(node);
        const float4* xr = (const float4*)(X + (size_t)un * 64);
        float acc = 0.0f;
#pragma unroll
        for (int j = 0; j < 16; ++j) {
            float4 xv = xr[j];
            acc = fmaf(xv.x, w[4 * j + 0], acc);
            acc = fmaf(xv.y, w[4 * j + 1], acc);
            acc = fmaf(xv.z, w[4 * j + 2], acc);
            acc = fmaf(xv.w, w[4 * j + 3], acc);
        }
        float v = (lane < 40) ? acc + bv : -INFINITY;
        float m = v;
#pragma unroll
        for (int o = 32; o > 0; o >>= 1) m = fmaxf(m, __shfl_xor(m, o, 64));
        float ex = (lane < 40) ? expf(v - m) : 0.0f;
        float s = ex;
#pragma unroll
        for (int o = 32; o > 0; o >>= 1) s += __shfl_xor(s, o, 64);
        if (lane < 40) out[(size_t)node * 40 + lane] = v - m - logf(s);
    }
}

extern "C" void kernel_launch(void* const* d_in, const int* in_sizes, int n_in,
                              void* d_out, int out_size, void* d_ws, size_t ws_size,
                              hipStream_t stream) {
    const float* x  = (const float*)d_in[0];
    const int*   ei = (const int*)d_in[1];
    const float* W1 = (const float*)d_in[2];
    const float* b1 = (const float*)d_in[3];
    const float* W2 = (const float*)d_in[4];
    const float* b2 = (const float*)d_in[5];
    const float* W3 = (const float*)d_in[6];
    const float* b3 = (const float*)d_in[7];
    float* out = (float*)d_out;

    const int N = in_sizes[0] / 128;
    const int E = in_sizes[1] / 2;
    const int* src = ei;
    const int* dst = ei + E;

    // ---- workspace layout ----
    char* ws = (char*)d_ws;
    float* hbuf  = (float*)ws;                ws += (size_t)N * 64 * sizeof(float); // 25.6 MB
    float* abuf  = (float*)ws;                ws += (size_t)N * 64 * sizeof(float); // 25.6 MB
    int*   esrc  = (int*)ws;                  ws += (size_t)E * sizeof(int);        // 4.8 MB
    int*   cnt   = (int*)ws;                  ws += (size_t)N * sizeof(int);
    int*   fill  = (int*)ws;                  ws += (size_t)N * sizeof(int);
    int*   rp    = (int*)ws;                  ws += (size_t)(N + 1) * sizeof(int);
    int*   bsum  = (int*)ws;                  ws += (size_t)SCAN_B * sizeof(int);
    float* dis   = (float*)ws;                ws += (size_t)N * sizeof(float);

    const int B = 256;
    const int nb = cdiv(N, SCAN_B);

    // ---- CSR build ----
    k_zero_i32<<<cdiv(N, B), B, 0, stream>>>(cnt, N);
    k_hist4<<<cdiv(E, B * 4), B, 0, stream>>>(dst, cnt, E);
    k_dis<<<cdiv(N, B), B, 0, stream>>>(cnt, dis, N);
    k_scan1<<<nb, SCAN_B, 0, stream>>>(cnt, rp, bsum, N);
    k_scan2<<<1, SCAN_B, 0, stream>>>(bsum, nb);
    k_scan3<<<cdiv(N + 1, SCAN_B), SCAN_B, 0, stream>>>(rp, bsum, fill, N, E);
    k_build4<<<cdiv(E, B * 4), B, 0, stream>>>(src, dst, fill, esrc, E);

    // ---- layer 1: Hs1 = (x@W1)*dis; a1 = relu(dis*(sum)+b1) ----
    k_gemm_lds<128><<<cdiv(N, 64), B, 0, stream>>>(x, W1, dis, hbuf, N);
    k_agg<0><<<cdiv(N, 4), B, 0, stream>>>(hbuf, dis, rp, esrc, b1, abuf, N);

    // ---- layer 2: Hs2 = (a1@W2)*dis; a2s = relu(dis*(sum)+b2)*dis ----
    k_gemm_lds<64><<<cdiv(N, 64), B, 0, stream>>>(abuf, W2, dis, hbuf, N);
    k_agg<1><<<cdiv(N, 4), B, 0, stream>>>(hbuf, dis, rp, esrc, b2, abuf, N);

    // ---- layer 3: g = dis*(sum of a2s); out = log_softmax(g@W3 + b3) ----
    k_agg<2><<<cdiv(N, 4), B, 0, stream>>>(abuf, dis, rp, esrc, nullptr, hbuf, N);
    const int NW = 4096;                       // 1024 blocks x 4 waves
    const int npw = cdiv(N, NW);
    k_w3lsm<<<NW / 4, B, 0, stream>>>(hbuf, W3, b3, out, N, npw);
}

// Round 12
// 407.164 us; speedup vs baseline: 1.1731x; 1.1731x over previous
//
#include <hip/hip_runtime.h>
#include <math.h>

// ---------------------------------------------------------------------------
// 3-layer GCN, CSR-gather formulation.
// Round 12: CSR build split into (a) k_hist_rank -- the degree-count atomic's
// return value IS the edge's within-dst rank, stored coalesced; (b) k_scatter
// -- no atomics: esrc[rp[d]+rank[e]] = src[e], 1 edge/thread, max TLP.
// R11's 4-edge/thread build lost 4x TLP and regressed (75->95us); lesson:
// on atomic/scatter paths TLP beats in-thread ILP.
// N=100000, E=1200000, F: 128 -> 64 -> 64 -> 40
// ---------------------------------------------------------------------------

static inline int cdiv(long a, int b) { return (int)((a + b - 1) / b); }

__global__ void k_zero_i32(int* __restrict__ p, int n) {
    int i = blockIdx.x * blockDim.x + threadIdx.x;
    if (i < n) p[i] = 0;
}

// degree histogram; atomic return = edge's rank within its destination
__global__ void k_hist_rank(const int* __restrict__ dst, int* __restrict__ cnt,
                            int* __restrict__ rank, int E) {
    int e = blockIdx.x * blockDim.x + threadIdx.x;
    if (e < E) rank[e] = atomicAdd(&cnt[dst[e]], 1);
}

__global__ void k_dis(const int* __restrict__ cnt, float* __restrict__ dis, int n) {
    int i = blockIdx.x * blockDim.x + threadIdx.x;
    if (i < n) dis[i] = rsqrtf(1.0f + (float)cnt[i]);  // +1 self-loop
}

// ---- 3-step exclusive scan of cnt[0..n) into rp[0..n], rp[n]=E ----
#define SCAN_B 1024
__global__ void k_scan1(const int* __restrict__ cnt, int* __restrict__ rp,
                        int* __restrict__ bsum, int n) {
    __shared__ int sm[SCAN_B];
    const int tid = threadIdx.x;
    const int gid = blockIdx.x * SCAN_B + tid;
    int v = (gid < n) ? cnt[gid] : 0;
    sm[tid] = v;
    __syncthreads();
    for (int off = 1; off < SCAN_B; off <<= 1) {
        int t = (tid >= off) ? sm[tid - off] : 0;
        __syncthreads();
        sm[tid] += t;
        __syncthreads();
    }
    if (gid < n) rp[gid] = sm[tid] - v;           // exclusive
    if (tid == SCAN_B - 1) bsum[blockIdx.x] = sm[tid];
}

__global__ void k_scan2(int* __restrict__ bsum, int nb) {
    __shared__ int sm[SCAN_B];
    const int tid = threadIdx.x;
    int v = (tid < nb) ? bsum[tid] : 0;
    sm[tid] = v;
    __syncthreads();
    for (int off = 1; off < SCAN_B; off <<= 1) {
        int t = (tid >= off) ? sm[tid - off] : 0;
        __syncthreads();
        sm[tid] += t;
        __syncthreads();
    }
    if (tid < nb) bsum[tid] = sm[tid] - v;        // exclusive
}

__global__ void k_scan3(int* __restrict__ rp, const int* __restrict__ bsum, int n, int E) {
    const int gid = blockIdx.x * SCAN_B + threadIdx.x;
    if (gid < n) rp[gid] += bsum[gid / SCAN_B];
    if (gid == n) rp[n] = E;
}

// CSR scatter, NO atomics: slot = rp[dst[e]] + rank[e]
__global__ void k_scatter(const int* __restrict__ src, const int* __restrict__ dst,
                          const int* __restrict__ rank, const int* __restrict__ rp,
                          int* __restrict__ esrc, int E) {
    int e = blockIdx.x * blockDim.x + threadIdx.x;
    if (e >= E) return;
    esrc[rp[dst[e]] + rank[e]] = src[e];
}

__device__ __forceinline__ void fma4(float a, const float4& w, float4& acc) {
    acc.x = fmaf(a, w.x, acc.x);
    acc.y = fmaf(a, w.y, acc.y);
    acc.z = fmaf(a, w.z, acc.z);
    acc.w = fmaf(a, w.w, acc.w);
}

// LDS-tiled GEMM with fused dis-scale: Hs[N,64] = (X[N,K] @ W[K,64]) * dis[row].
template<int K>
__global__ __launch_bounds__(256, 2)
void k_gemm_lds(const float* __restrict__ X, const float* __restrict__ W,
                const float* __restrict__ dis, float* __restrict__ H, int N) {
    constexpr int KP = K + 4;                 // padded X row stride (floats)
    __shared__ float xs[64 * KP];
    __shared__ float wsh[K * 64];
    const int tid = threadIdx.x;
    const int tx = tid & 15;                  // col group (4 cols)
    const int ty = tid >> 4;                  // row group (4 rows)
    const int row0 = blockIdx.x * 64;

    // stage W: K*16 float4, fully coalesced
    {
        const float4* Wg = (const float4*)W;
        float4* Wl = (float4*)wsh;
#pragma unroll
        for (int i = 0; i < K * 16 / 256; ++i)
            Wl[i * 256 + tid] = Wg[i * 256 + tid];
    }
    // stage X tile: 64 rows x K floats (row-clamped), padded LDS rows
    {
        constexpr int F4 = K / 4;             // float4 per row
        for (int i = tid; i < 64 * F4; i += 256) {
            int r = i / F4, c = i - r * F4;
            int gr = min(row0 + r, N - 1);
            float4 v = *(const float4*)(X + (size_t)gr * K + c * 4);
            *(float4*)(xs + r * KP + c * 4) = v;
        }
    }
    __syncthreads();

    float4 acc0 = {0.f, 0.f, 0.f, 0.f};
    float4 acc1 = {0.f, 0.f, 0.f, 0.f};
    float4 acc2 = {0.f, 0.f, 0.f, 0.f};
    float4 acc3 = {0.f, 0.f, 0.f, 0.f};

    const float* xr0 = xs + (ty * 4 + 0) * KP;
    const float* xr1 = xs + (ty * 4 + 1) * KP;
    const float* xr2 = xs + (ty * 4 + 2) * KP;
    const float* xr3 = xs + (ty * 4 + 3) * KP;

#pragma unroll 2
    for (int k = 0; k < K; k += 4) {
        float4 w0 = *(const float4*)(wsh + (k + 0) * 64 + tx * 4);
        float4 w1 = *(const float4*)(wsh + (k + 1) * 64 + tx * 4);
        float4 w2 = *(const float4*)(wsh + (k + 2) * 64 + tx * 4);
        float4 w3 = *(const float4*)(wsh + (k + 3) * 64 + tx * 4);
        float4 xa = *(const float4*)(xr0 + k);
        float4 xb = *(const float4*)(xr1 + k);
        float4 xc = *(const float4*)(xr2 + k);
        float4 xd = *(const float4*)(xr3 + k);

        fma4(xa.x, w0, acc0); fma4(xa.y, w1, acc0); fma4(xa.z, w2, acc0); fma4(xa.w, w3, acc0);
        fma4(xb.x, w0, acc1); fma4(xb.y, w1, acc1); fma4(xb.z, w2, acc1); fma4(xb.w, w3, acc1);
        fma4(xc.x, w0, acc2); fma4(xc.y, w1, acc2); fma4(xc.z, w2, acc2); fma4(xc.w, w3, acc2);
        fma4(xd.x, w0, acc3); fma4(xd.y, w1, acc3); fma4(xd.z, w2, acc3); fma4(xd.w, w3, acc3);
    }

    const int r = row0 + ty * 4;
    float* hp = H + (size_t)r * 64 + tx * 4;
    if (r + 0 < N) { float d0 = dis[r + 0];
        acc0.x *= d0; acc0.y *= d0; acc0.z *= d0; acc0.w *= d0;
        *(float4*)(hp + 0 * 64) = acc0; }
    if (r + 1 < N) { float d1 = dis[r + 1];
        acc1.x *= d1; acc1.y *= d1; acc1.z *= d1; acc1.w *= d1;
        *(float4*)(hp + 1 * 64) = acc1; }
    if (r + 2 < N) { float d2 = dis[r + 2];
        acc2.x *= d2; acc2.y *= d2; acc2.z *= d2; acc2.w *= d2;
        *(float4*)(hp + 2 * 64) = acc2; }
    if (r + 3 < N) { float d3 = dis[r + 3];
        acc3.x *= d3; acc3.y *= d3; acc3.z *= d3; acc3.w *= d3;
        *(float4*)(hp + 3 * 64) = acc3; }
}

// Wave-per-node segmented row-sum, quad-per-edge.
// Input Hs = h*dis.  t = dis[d] * (Hs[d] + sum_{in-edges} Hs[s]).
// MODE 0: A = relu(t + bias)              (layer 1)
// MODE 1: A = relu(t + bias) * dis[d]     (layer 2 -> pre-scaled for layer-3 agg)
// MODE 2: A = t                           (layer 3 pre-GEMM aggregate)
template<int MODE>
__global__ __launch_bounds__(256, 8)
void k_agg(const float* __restrict__ Hs, const float* __restrict__ dis,
           const int* __restrict__ rp, const int* __restrict__ esrc,
           const float* __restrict__ bias, float* __restrict__ A, int N) {
    const int wave = threadIdx.x >> 6;
    const int lane = threadIdx.x & 63;
    const int node = blockIdx.x * (blockDim.x >> 6) + wave;
    if (node >= N) return;
    const int q  = lane >> 4;          // quad 0..3 -> interleaved edges
    const int f4 = lane & 15;          // float4 index within the 64-f row

    const int e0 = rp[node];
    const int e1 = rp[node + 1];
    float4 acc = {0.f, 0.f, 0.f, 0.f};
    int e = e0 + q;
    for (; e + 4 < e1; e += 8) {       // 2 edges per quad per round: 8 rows in flight
        int s0 = esrc[e];
        int s1 = esrc[e + 4];
        float4 h0 = *(const float4*)(Hs + (size_t)s0 * 64 + f4 * 4);
        float4 h1 = *(const float4*)(Hs + (size_t)s1 * 64 + f4 * 4);
        acc.x += h0.x + h1.x;
        acc.y += h0.y + h1.y;
        acc.z += h0.z + h1.z;
        acc.w += h0.w + h1.w;
    }
    for (; e < e1; e += 4) {
        int s = esrc[e];
        float4 h = *(const float4*)(Hs + (size_t)s * 64 + f4 * 4);
        acc.x += h.x; acc.y += h.y; acc.z += h.z; acc.w += h.w;
    }
    // cross-quad reduce (after: lanes 0..15 hold the full row sum)
    acc.x += __shfl_xor(acc.x, 16, 64);
    acc.y += __shfl_xor(acc.y, 16, 64);
    acc.z += __shfl_xor(acc.z, 16, 64);
    acc.w += __shfl_xor(acc.w, 16, 64);
    acc.x += __shfl_xor(acc.x, 32, 64);
    acc.y += __shfl_xor(acc.y, 32, 64);
    acc.z += __shfl_xor(acc.z, 32, 64);
    acc.w += __shfl_xor(acc.w, 32, 64);

    if (lane < 16) {
        const float dd = dis[node];
        float4 self = *(const float4*)(Hs + (size_t)node * 64 + lane * 4);
        float4 v;
        v.x = (acc.x + self.x) * dd;
        v.y = (acc.y + self.y) * dd;
        v.z = (acc.z + self.z) * dd;
        v.w = (acc.w + self.w) * dd;
        if (MODE == 0 || MODE == 1) {
            float4 bv = ((const float4*)bias)[lane];
            v.x = fmaxf(v.x + bv.x, 0.f);
            v.y = fmaxf(v.y + bv.y, 0.f);
            v.z = fmaxf(v.z + bv.z, 0.f);
            v.w = fmaxf(v.w + bv.w, 0.f);
        }
        if (MODE == 1) { v.x *= dd; v.y *= dd; v.z *= dd; v.w *= dd; }
        *(float4*)(A + (size_t)node * 64 + lane * 4) = v;
    }
}

// Final layer: out[n,:40] = log_softmax(X[n,:64] @ W3 + b3).
// Lane c holds W3[:,c] in 64 VGPRs; X row via wave-uniform loads.
__global__ __launch_bounds__(256, 4)
void k_w3lsm(const float* __restrict__ X, const float* __restrict__ W,
             const float* __restrict__ bias, float* __restrict__ out,
             int N, int npw) {
    const int wid  = blockIdx.x * (blockDim.x >> 6) + (threadIdx.x >> 6);
    const int lane = threadIdx.x & 63;
    const int cl   = (lane < 40) ? lane : 0;

    float w[64];
#pragma unroll
    for (int k = 0; k < 64; ++k) w[k] = W[k * 40 + cl];
    const float bv = bias[cl];

    const int n0 = wid * npw;
    const int n1 = min(n0 + npw, N);
    for (int node = n0; node < n1; ++node) {
        const int un = __builtin_amdgcn_readfirstlane(node);
        const float4* xr = (const float4*)(X + (size_t)un * 64);
        float acc = 0.0f;
#pragma unroll
        for (int j = 0; j < 16; ++j) {
            float4 xv = xr[j];
            acc = fmaf(xv.x, w[4 * j + 0], acc);
            acc = fmaf(xv.y, w[4 * j + 1], acc);
            acc = fmaf(xv.z, w[4 * j + 2], acc);
            acc = fmaf(xv.w, w[4 * j + 3], acc);
        }
        float v = (lane < 40) ? acc + bv : -INFINITY;
        float m = v;
#pragma unroll
        for (int o = 32; o > 0; o >>= 1) m = fmaxf(m, __shfl_xor(m, o, 64));
        float ex = (lane < 40) ? expf(v - m) : 0.0f;
        float s = ex;
#pragma unroll
        for (int o = 32; o > 0; o >>= 1) s += __shfl_xor(s, o, 64);
        if (lane < 40) out[(size_t)node * 40 + lane] = v - m - logf(s);
    }
}

extern "C" void kernel_launch(void* const* d_in, const int* in_sizes, int n_in,
                              void* d_out, int out_size, void* d_ws, size_t ws_size,
                              hipStream_t stream) {
    const float* x  = (const float*)d_in[0];
    const int*   ei = (const int*)d_in[1];
    const float* W1 = (const float*)d_in[2];
    const float* b1 = (const float*)d_in[3];
    const float* W2 = (const float*)d_in[4];
    const float* b2 = (const float*)d_in[5];
    const float* W3 = (const float*)d_in[6];
    const float* b3 = (const float*)d_in[7];
    float* out = (float*)d_out;

    const int N = in_sizes[0] / 128;
    const int E = in_sizes[1] / 2;
    const int* src = ei;
    const int* dst = ei + E;

    // ---- workspace layout ----
    char* ws = (char*)d_ws;
    float* hbuf  = (float*)ws;                ws += (size_t)N * 64 * sizeof(float); // 25.6 MB
    float* abuf  = (float*)ws;                ws += (size_t)N * 64 * sizeof(float); // 25.6 MB
    int*   esrc  = (int*)ws;                  ws += (size_t)E * sizeof(int);        // 4.8 MB
    int*   rank  = (int*)ws;                  ws += (size_t)E * sizeof(int);        // 4.8 MB
    int*   cnt   = (int*)ws;                  ws += (size_t)N * sizeof(int);
    int*   rp    = (int*)ws;                  ws += (size_t)(N + 1) * sizeof(int);
    int*   bsum  = (int*)ws;                  ws += (size_t)SCAN_B * sizeof(int);
    float* dis   = (float*)ws;                ws += (size_t)N * sizeof(float);

    const int B = 256;
    const int nb = cdiv(N, SCAN_B);

    // ---- CSR build (rank-from-histogram, atomic-free scatter) ----
    k_zero_i32<<<cdiv(N, B), B, 0, stream>>>(cnt, N);
    k_hist_rank<<<cdiv(E, B), B, 0, stream>>>(dst, cnt, rank, E);
    k_dis<<<cdiv(N, B), B, 0, stream>>>(cnt, dis, N);
    k_scan1<<<nb, SCAN_B, 0, stream>>>(cnt, rp, bsum, N);
    k_scan2<<<1, SCAN_B, 0, stream>>>(bsum, nb);
    k_scan3<<<cdiv(N + 1, SCAN_B), SCAN_B, 0, stream>>>(rp, bsum, N, E);
    k_scatter<<<cdiv(E, B), B, 0, stream>>>(src, dst, rank, rp, esrc, E);

    // ---- layer 1: Hs1 = (x@W1)*dis; a1 = relu(dis*(sum)+b1) ----
    k_gemm_lds<128><<<cdiv(N, 64), B, 0, stream>>>(x, W1, dis, hbuf, N);
    k_agg<0><<<cdiv(N, 4), B, 0, stream>>>(hbuf, dis, rp, esrc, b1, abuf, N);

    // ---- layer 2: Hs2 = (a1@W2)*dis; a2s = relu(dis*(sum)+b2)*dis ----
    k_gemm_lds<64><<<cdiv(N, 64), B, 0, stream>>>(abuf, W2, dis, hbuf, N);
    k_agg<1><<<cdiv(N, 4), B, 0, stream>>>(hbuf, dis, rp, esrc, b2, abuf, N);

    // ---- layer 3: g = dis*(sum of a2s); out = log_softmax(g@W3 + b3) ----
    k_agg<2><<<cdiv(N, 4), B, 0, stream>>>(abuf, dis, rp, esrc, nullptr, hbuf, N);
    const int NW = 4096;                       // 1024 blocks x 4 waves
    const int npw = cdiv(N, NW);
    k_w3lsm<<<NW / 4, B, 0, stream>>>(hbuf, W3, b3, out, N, npw);
}

// Round 13
// 382.285 us; speedup vs baseline: 1.2494x; 1.0651x over previous
//
#include <hip/hip_runtime.h>
#include <math.h>

// ---------------------------------------------------------------------------
// 3-layer GCN, CSR-gather formulation.
// Round 13: bf16 storage (RNE) for the three GATHER targets (Hs1, Hs2, a2s):
// 256B fp32 rows -> 128B bf16 rows = 1 L2 line per edge gather instead of 2.
// All accumulation fp32; coalesced-read buffers (a1 GEMM input, g w3lsm
// input) stay fp32. agg was fetch-bound: 147MB @ 2.8TB/s L2-miss path.
// N=100000, E=1200000, F: 128 -> 64 -> 64 -> 40
// ---------------------------------------------------------------------------

static inline int cdiv(long a, int b) { return (int)((a + b - 1) / b); }

// ---- bf16 helpers (RNE) ----
__device__ __forceinline__ unsigned short f2bf(float f) {
    unsigned u = __float_as_uint(f);
    u += 0x7fffu + ((u >> 16) & 1u);
    return (unsigned short)(u >> 16);
}
__device__ __forceinline__ float bf2f(unsigned short b) {
    return __uint_as_float(((unsigned)b) << 16);
}

__global__ void k_zero_i32(int* __restrict__ p, int n) {
    int i = blockIdx.x * blockDim.x + threadIdx.x;
    if (i < n) p[i] = 0;
}

// degree histogram; atomic return = edge's rank within its destination
__global__ void k_hist_rank(const int* __restrict__ dst, int* __restrict__ cnt,
                            int* __restrict__ rank, int E) {
    int e = blockIdx.x * blockDim.x + threadIdx.x;
    if (e < E) rank[e] = atomicAdd(&cnt[dst[e]], 1);
}

__global__ void k_dis(const int* __restrict__ cnt, float* __restrict__ dis, int n) {
    int i = blockIdx.x * blockDim.x + threadIdx.x;
    if (i < n) dis[i] = rsqrtf(1.0f + (float)cnt[i]);  // +1 self-loop
}

// ---- 3-step exclusive scan of cnt[0..n) into rp[0..n], rp[n]=E ----
#define SCAN_B 1024
__global__ void k_scan1(const int* __restrict__ cnt, int* __restrict__ rp,
                        int* __restrict__ bsum, int n) {
    __shared__ int sm[SCAN_B];
    const int tid = threadIdx.x;
    const int gid = blockIdx.x * SCAN_B + tid;
    int v = (gid < n) ? cnt[gid] : 0;
    sm[tid] = v;
    __syncthreads();
    for (int off = 1; off < SCAN_B; off <<= 1) {
        int t = (tid >= off) ? sm[tid - off] : 0;
        __syncthreads();
        sm[tid] += t;
        __syncthreads();
    }
    if (gid < n) rp[gid] = sm[tid] - v;           // exclusive
    if (tid == SCAN_B - 1) bsum[blockIdx.x] = sm[tid];
}

__global__ void k_scan2(int* __restrict__ bsum, int nb) {
    __shared__ int sm[SCAN_B];
    const int tid = threadIdx.x;
    int v = (tid < nb) ? bsum[tid] : 0;
    sm[tid] = v;
    __syncthreads();
    for (int off = 1; off < SCAN_B; off <<= 1) {
        int t = (tid >= off) ? sm[tid - off] : 0;
        __syncthreads();
        sm[tid] += t;
        __syncthreads();
    }
    if (tid < nb) bsum[tid] = sm[tid] - v;        // exclusive
}

__global__ void k_scan3(int* __restrict__ rp, const int* __restrict__ bsum, int n, int E) {
    const int gid = blockIdx.x * SCAN_B + threadIdx.x;
    if (gid < n) rp[gid] += bsum[gid / SCAN_B];
    if (gid == n) rp[n] = E;
}

// CSR scatter, NO atomics: slot = rp[dst[e]] + rank[e]
__global__ void k_scatter(const int* __restrict__ src, const int* __restrict__ dst,
                          const int* __restrict__ rank, const int* __restrict__ rp,
                          int* __restrict__ esrc, int E) {
    int e = blockIdx.x * blockDim.x + threadIdx.x;
    if (e >= E) return;
    esrc[rp[dst[e]] + rank[e]] = src[e];
}

__device__ __forceinline__ void fma4(float a, const float4& w, float4& acc) {
    acc.x = fmaf(a, w.x, acc.x);
    acc.y = fmaf(a, w.y, acc.y);
    acc.z = fmaf(a, w.z, acc.z);
    acc.w = fmaf(a, w.w, acc.w);
}

// LDS-tiled GEMM with fused dis-scale: Hs[N,64] = (X[N,K] @ W[K,64]) * dis[row].
// BF16OUT: store rows as bf16 (gather target); else fp32.
template<int K, bool BF16OUT>
__global__ __launch_bounds__(256, 2)
void k_gemm_lds(const float* __restrict__ X, const float* __restrict__ W,
                const float* __restrict__ dis, void* __restrict__ Hout, int N) {
    constexpr int KP = K + 4;                 // padded X row stride (floats)
    __shared__ float xs[64 * KP];
    __shared__ float wsh[K * 64];
    const int tid = threadIdx.x;
    const int tx = tid & 15;                  // col group (4 cols)
    const int ty = tid >> 4;                  // row group (4 rows)
    const int row0 = blockIdx.x * 64;

    // stage W: K*16 float4, fully coalesced
    {
        const float4* Wg = (const float4*)W;
        float4* Wl = (float4*)wsh;
#pragma unroll
        for (int i = 0; i < K * 16 / 256; ++i)
            Wl[i * 256 + tid] = Wg[i * 256 + tid];
    }
    // stage X tile: 64 rows x K floats (row-clamped), padded LDS rows
    {
        constexpr int F4 = K / 4;             // float4 per row
        for (int i = tid; i < 64 * F4; i += 256) {
            int r = i / F4, c = i - r * F4;
            int gr = min(row0 + r, N - 1);
            float4 v = *(const float4*)(X + (size_t)gr * K + c * 4);
            *(float4*)(xs + r * KP + c * 4) = v;
        }
    }
    __syncthreads();

    float4 acc0 = {0.f, 0.f, 0.f, 0.f};
    float4 acc1 = {0.f, 0.f, 0.f, 0.f};
    float4 acc2 = {0.f, 0.f, 0.f, 0.f};
    float4 acc3 = {0.f, 0.f, 0.f, 0.f};

    const float* xr0 = xs + (ty * 4 + 0) * KP;
    const float* xr1 = xs + (ty * 4 + 1) * KP;
    const float* xr2 = xs + (ty * 4 + 2) * KP;
    const float* xr3 = xs + (ty * 4 + 3) * KP;

#pragma unroll 2
    for (int k = 0; k < K; k += 4) {
        float4 w0 = *(const float4*)(wsh + (k + 0) * 64 + tx * 4);
        float4 w1 = *(const float4*)(wsh + (k + 1) * 64 + tx * 4);
        float4 w2 = *(const float4*)(wsh + (k + 2) * 64 + tx * 4);
        float4 w3 = *(const float4*)(wsh + (k + 3) * 64 + tx * 4);
        float4 xa = *(const float4*)(xr0 + k);
        float4 xb = *(const float4*)(xr1 + k);
        float4 xc = *(const float4*)(xr2 + k);
        float4 xd = *(const float4*)(xr3 + k);

        fma4(xa.x, w0, acc0); fma4(xa.y, w1, acc0); fma4(xa.z, w2, acc0); fma4(xa.w, w3, acc0);
        fma4(xb.x, w0, acc1); fma4(xb.y, w1, acc1); fma4(xb.z, w2, acc1); fma4(xb.w, w3, acc1);
        fma4(xc.x, w0, acc2); fma4(xc.y, w1, acc2); fma4(xc.z, w2, acc2); fma4(xc.w, w3, acc2);
        fma4(xd.x, w0, acc3); fma4(xd.y, w1, acc3); fma4(xd.z, w2, acc3); fma4(xd.w, w3, acc3);
    }

    const int r = row0 + ty * 4;
#pragma unroll
    for (int i = 0; i < 4; ++i) {
        if (r + i >= N) break;
        float4 a = (i == 0) ? acc0 : (i == 1) ? acc1 : (i == 2) ? acc2 : acc3;
        float d = dis[r + i];
        a.x *= d; a.y *= d; a.z *= d; a.w *= d;
        if (BF16OUT) {
            ushort4 o;
            o.x = f2bf(a.x); o.y = f2bf(a.y); o.z = f2bf(a.z); o.w = f2bf(a.w);
            *(ushort4*)((unsigned short*)Hout + (size_t)(r + i) * 64 + tx * 4) = o;
        } else {
            *(float4*)((float*)Hout + (size_t)(r + i) * 64 + tx * 4) = a;
        }
    }
}

// Wave-per-node segmented row-sum, quad-per-edge, bf16 gather rows (128 B).
// Input Hs = bf16(h*dis).  t = dis[d] * (Hs[d] + sum_{in-edges} Hs[s]).
// MODE 0: A = relu(t + bias)           -> fp32  (layer 1, GEMM input)
// MODE 1: A = relu(t + bias) * dis[d]  -> bf16  (layer 2 -> layer-3 gather)
// MODE 2: A = t                        -> fp32  (layer 3, w3lsm input)
template<int MODE>
__global__ __launch_bounds__(256, 8)
void k_agg(const unsigned short* __restrict__ Hs, const float* __restrict__ dis,
           const int* __restrict__ rp, const int* __restrict__ esrc,
           const float* __restrict__ bias, void* __restrict__ A, int N) {
    const int wave = threadIdx.x >> 6;
    const int lane = threadIdx.x & 63;
    const int node = blockIdx.x * (blockDim.x >> 6) + wave;
    if (node >= N) return;
    const int q  = lane >> 4;          // quad 0..3 -> interleaved edges
    const int f4 = lane & 15;          // 4-feature group within the 64-f row

    const int e0 = rp[node];
    const int e1 = rp[node + 1];
    float4 acc = {0.f, 0.f, 0.f, 0.f};
    int e = e0 + q;
    for (; e + 4 < e1; e += 8) {       // 2 edges per quad per round
        int s0 = esrc[e];
        int s1 = esrc[e + 4];
        ushort4 h0 = *(const ushort4*)(Hs + (size_t)s0 * 64 + f4 * 4);
        ushort4 h1 = *(const ushort4*)(Hs + (size_t)s1 * 64 + f4 * 4);
        acc.x += bf2f(h0.x) + bf2f(h1.x);
        acc.y += bf2f(h0.y) + bf2f(h1.y);
        acc.z += bf2f(h0.z) + bf2f(h1.z);
        acc.w += bf2f(h0.w) + bf2f(h1.w);
    }
    for (; e < e1; e += 4) {
        int s = esrc[e];
        ushort4 h = *(const ushort4*)(Hs + (size_t)s * 64 + f4 * 4);
        acc.x += bf2f(h.x); acc.y += bf2f(h.y); acc.z += bf2f(h.z); acc.w += bf2f(h.w);
    }
    // cross-quad reduce (after: lanes 0..15 hold the full row sum)
    acc.x += __shfl_xor(acc.x, 16, 64);
    acc.y += __shfl_xor(acc.y, 16, 64);
    acc.z += __shfl_xor(acc.z, 16, 64);
    acc.w += __shfl_xor(acc.w, 16, 64);
    acc.x += __shfl_xor(acc.x, 32, 64);
    acc.y += __shfl_xor(acc.y, 32, 64);
    acc.z += __shfl_xor(acc.z, 32, 64);
    acc.w += __shfl_xor(acc.w, 32, 64);

    if (lane < 16) {
        const float dd = dis[node];
        ushort4 sh = *(const ushort4*)(Hs + (size_t)node * 64 + lane * 4);
        float4 v;
        v.x = (acc.x + bf2f(sh.x)) * dd;
        v.y = (acc.y + bf2f(sh.y)) * dd;
        v.z = (acc.z + bf2f(sh.z)) * dd;
        v.w = (acc.w + bf2f(sh.w)) * dd;
        if (MODE == 0 || MODE == 1) {
            float4 bv = ((const float4*)bias)[lane];
            v.x = fmaxf(v.x + bv.x, 0.f);
            v.y = fmaxf(v.y + bv.y, 0.f);
            v.z = fmaxf(v.z + bv.z, 0.f);
            v.w = fmaxf(v.w + bv.w, 0.f);
        }
        if (MODE == 1) {
            v.x *= dd; v.y *= dd; v.z *= dd; v.w *= dd;
            ushort4 o;
            o.x = f2bf(v.x); o.y = f2bf(v.y); o.z = f2bf(v.z); o.w = f2bf(v.w);
            *(ushort4*)((unsigned short*)A + (size_t)node * 64 + lane * 4) = o;
        } else {
            *(float4*)((float*)A + (size_t)node * 64 + lane * 4) = v;
        }
    }
}

// Final layer: out[n,:40] = log_softmax(X[n,:64] @ W3 + b3).
// Lane c holds W3[:,c] in 64 VGPRs; X row via wave-uniform loads.
__global__ __launch_bounds__(256, 4)
void k_w3lsm(const float* __restrict__ X, const float* __restrict__ W,
             const float* __restrict__ bias, float* __restrict__ out,
             int N, int npw) {
    const int wid  = blockIdx.x * (blockDim.x >> 6) + (threadIdx.x >> 6);
    const int lane = threadIdx.x & 63;
    const int cl   = (lane < 40) ? lane : 0;

    float w[64];
#pragma unroll
    for (int k = 0; k < 64; ++k) w[k] = W[k * 40 + cl];
    const float bv = bias[cl];

    const int n0 = wid * npw;
    const int n1 = min(n0 + npw, N);
    for (int node = n0; node < n1; ++node) {
        const int un = __builtin_amdgcn_readfirstlane(node);
        const float4* xr = (const float4*)(X + (size_t)un * 64);
        float acc = 0.0f;
#pragma unroll
        for (int j = 0; j < 16; ++j) {
            float4 xv = xr[j];
            acc = fmaf(xv.x, w[4 * j + 0], acc);
            acc = fmaf(xv.y, w[4 * j + 1], acc);
            acc = fmaf(xv.z, w[4 * j + 2], acc);
            acc = fmaf(xv.w, w[4 * j + 3], acc);
        }
        float v = (lane < 40) ? acc + bv : -INFINITY;
        float m = v;
#pragma unroll
        for (int o = 32; o > 0; o >>= 1) m = fmaxf(m, __shfl_xor(m, o, 64));
        float ex = (lane < 40) ? expf(v - m) : 0.0f;
        float s = ex;
#pragma unroll
        for (int o = 32; o > 0; o >>= 1) s += __shfl_xor(s, o, 64);
        if (lane < 40) out[(size_t)node * 40 + lane] = v - m - logf(s);
    }
}

extern "C" void kernel_launch(void* const* d_in, const int* in_sizes, int n_in,
                              void* d_out, int out_size, void* d_ws, size_t ws_size,
                              hipStream_t stream) {
    const float* x  = (const float*)d_in[0];
    const int*   ei = (const int*)d_in[1];
    const float* W1 = (const float*)d_in[2];
    const float* b1 = (const float*)d_in[3];
    const float* W2 = (const float*)d_in[4];
    const float* b2 = (const float*)d_in[5];
    const float* W3 = (const float*)d_in[6];
    const float* b3 = (const float*)d_in[7];
    float* out = (float*)d_out;

    const int N = in_sizes[0] / 128;
    const int E = in_sizes[1] / 2;
    const int* src = ei;
    const int* dst = ei + E;

    // ---- workspace layout ----
    // buf0: Hs1 bf16 -> Hs2 bf16 -> g fp32   (sized for fp32)
    // buf1: a1 fp32 -> a2s bf16              (sized for fp32)
    char* ws = (char*)d_ws;
    char* buf0  = ws;                         ws += (size_t)N * 64 * sizeof(float); // 25.6 MB
    char* buf1  = ws;                         ws += (size_t)N * 64 * sizeof(float); // 25.6 MB
    int*   esrc  = (int*)ws;                  ws += (size_t)E * sizeof(int);        // 4.8 MB
    int*   rank  = (int*)ws;                  ws += (size_t)E * sizeof(int);        // 4.8 MB
    int*   cnt   = (int*)ws;                  ws += (size_t)N * sizeof(int);
    int*   rp    = (int*)ws;                  ws += (size_t)(N + 1) * sizeof(int);
    int*   bsum  = (int*)ws;                  ws += (size_t)SCAN_B * sizeof(int);
    float* dis   = (float*)ws;                ws += (size_t)N * sizeof(float);

    const int B = 256;
    const int nb = cdiv(N, SCAN_B);

    // ---- CSR build (rank-from-histogram, atomic-free scatter) ----
    k_zero_i32<<<cdiv(N, B), B, 0, stream>>>(cnt, N);
    k_hist_rank<<<cdiv(E, B), B, 0, stream>>>(dst, cnt, rank, E);
    k_dis<<<cdiv(N, B), B, 0, stream>>>(cnt, dis, N);
    k_scan1<<<nb, SCAN_B, 0, stream>>>(cnt, rp, bsum, N);
    k_scan2<<<1, SCAN_B, 0, stream>>>(bsum, nb);
    k_scan3<<<cdiv(N + 1, SCAN_B), SCAN_B, 0, stream>>>(rp, bsum, N, E);
    k_scatter<<<cdiv(E, B), B, 0, stream>>>(src, dst, rank, rp, esrc, E);

    // ---- layer 1: Hs1 = bf16((x@W1)*dis); a1 = relu(dis*sum + b1) fp32 ----
    k_gemm_lds<128, true><<<cdiv(N, 64), B, 0, stream>>>(x, W1, dis, buf0, N);
    k_agg<0><<<cdiv(N, 4), B, 0, stream>>>((const unsigned short*)buf0, dis, rp, esrc, b1, buf1, N);

    // ---- layer 2: Hs2 = bf16((a1@W2)*dis); a2s = bf16(relu(dis*sum+b2)*dis) ----
    k_gemm_lds<64, true><<<cdiv(N, 64), B, 0, stream>>>((const float*)buf1, W2, dis, buf0, N);
    k_agg<1><<<cdiv(N, 4), B, 0, stream>>>((const unsigned short*)buf0, dis, rp, esrc, b2, buf1, N);

    // ---- layer 3: g = dis*(sum of a2s) fp32; out = log_softmax(g@W3 + b3) ----
    k_agg<2><<<cdiv(N, 4), B, 0, stream>>>((const unsigned short*)buf1, dis, rp, esrc, nullptr, buf0, N);
    const int NW = 4096;                       // 1024 blocks x 4 waves
    const int npw = cdiv(N, NW);
    k_w3lsm<<<NW / 4, B, 0, stream>>>((const float*)buf0, W3, b3, out, N, npw);
}